// Round 13
// baseline (160.211 us; speedup 1.0000x reference)
//
#include <hip/hip_runtime.h>
#include <math.h>

#define NND 1024

#define STEP_     (5.0f/9.0f)
#define INV_STEP_ 1.8f
#define SQ3_      1.73205080756887729f
#define INV_SQ3_  0.57735026918962576f
#define INV_NN_   0.03126527053f      /* 1/sqrt(1023) */
#define INV_S8_   0.35355339059327373f
#define INV_S32_  0.17677669529663687f
#define LOG2E_    1.44269504088896341f

typedef float f32x4 __attribute__((ext_vector_type(4)));
typedef short short8 __attribute__((ext_vector_type(8)));

__device__ __forceinline__ float fast_rcp(float x){ return __builtin_amdgcn_rcpf(x); }
__device__ __forceinline__ float silu_f(float t){
    return t * fast_rcp(1.0f + __builtin_amdgcn_exp2f(t * (-LOG2E_)));
}
__device__ __forceinline__ float sigm_f(float t){
    return fast_rcp(1.0f + __builtin_amdgcn_exp2f(t * (-LOG2E_)));
}
// packed bf16 convert. Internal half order σ UNKNOWN — every use pairs the SAME
// even-k (x[k0],x[k0+1]) structure on BOTH MFMA operands, so σ cancels.
__device__ __forceinline__ int cvt_pk(float a, float b){
    int r;
    asm("v_cvt_pk_bf16_f32 %0, %1, %2" : "=v"(r) : "v"(a), "v"(b));
    return r;
}

// fragment via cvt_pk pairs: lane holds m/n = ncol, k = kbase + [dword i covers
// k0=kbase+2i, k0+1 in σ-order]. Pairs with any other cvt_pk-built operand.
template<int KREAL, int NCOLS>
__device__ __forceinline__ short8 load_bfrag_pk(const float* __restrict__ W, int kbase, int ncol){
    union { short8 s8; int u[4]; } f;
#pragma unroll
    for (int i = 0; i < 4; i++){
        int k0 = kbase + 2*i, k1 = k0 + 1;
        float v0 = (k0 < KREAL && ncol < NCOLS) ? W[k0*NCOLS + ncol] : 0.f;
        float v1 = (k1 < KREAL && ncol < NCOLS) ? W[k1*NCOLS + ncol] : 0.f;
        f.u[i] = cvt_pk(v0, v1);
    }
    return f.s8;
}

// hT staging (dword layout = round 6/7/10/12, verified passing):
// h[j][src] pairs (j0=2R, j0+1) in dword at byte (R^xbit)*64 + src*4.
// Write: R = 8t+2g+p, xbit = g>>1.  Read: R = 16s+4g+i, xbit = g&1.
// Within-tile pipeline: GEMM2 s-step reads R in [16s,16s+16) = exactly
// GEMM1 t=2s,2s+1 writes; issue order  w(2s),w(2s+1) -> rd(s) -> w(2s+2),
// w(2s+3) -> mfma(s)  lets the compiler use counted lgkmcnt (LDS completes
// in-order), hiding read latency under the next GEMM1 pair.

union HF { short8 s8; int i4[4]; };

#define G1STEP(t) do { \
    f32x4 c1 = __builtin_amdgcn_mfma_f32_16x16x32_bf16(w1f[t], af, zero4, 0, 0, 0); \
    int R0 = 8*(t) + 2*g; \
    *(int*)(hb + (((R0    ) ^ wX) << 6) + cb) = cvt_pk(silu_f(c1[0]), silu_f(c1[1])); \
    *(int*)(hb + (((R0 + 1) ^ wX) << 6) + cb) = cvt_pk(silu_f(c1[2]), silu_f(c1[3])); \
} while(0)

#define RD4(s, u_) do { \
    u_.i4[0] = *(const int*)(hb + (((16*(s) + 4*g + 0) ^ rX) << 6) + cb); \
    u_.i4[1] = *(const int*)(hb + (((16*(s) + 4*g + 1) ^ rX) << 6) + cb); \
    u_.i4[2] = *(const int*)(hb + (((16*(s) + 4*g + 2) ^ rX) << 6) + cb); \
    u_.i4[3] = *(const int*)(hb + (((16*(s) + 4*g + 3) ^ rX) << 6) + cb); \
} while(0)

// ---------------- Kernel A: node pre-GEMMs
__global__ __launch_bounds__(64) void k_node_pre(
    const float* __restrict__ x, const float* __restrict__ sc1_w,
    const float* __restrict__ lin1a_w, float* __restrict__ sc, float* __restrict__ xl)
{
    int n = blockIdx.x * blockDim.x + threadIdx.x;
    if (n >= NND) return;
    float xi[8];
#pragma unroll
    for (int i = 0; i < 8; i++) xi[i] = x[n*8 + i];
#pragma unroll
    for (int k = 0; k < 32; k++){
        float a = 0.f;
#pragma unroll
        for (int i = 0; i < 8; i++) a += xi[i] * sc1_w[i*32 + k];
        sc[n*32 + k] = a * INV_S8_;
    }
#pragma unroll
    for (int k = 0; k < 8; k++){
        float a = 0.f;
#pragma unroll
        for (int i = 0; i < 8; i++) a += xi[i] * lin1a_w[i*8 + k];
        xl[n*8 + k] = a * INV_S8_;
    }
}

// ---------------- Kernel B: edge pass 1 (within-tile pipelined MFMA)
__global__ __launch_bounds__(256,3) void k_edge1_mfma(
    const float* __restrict__ pos, const float* __restrict__ xl,
    const float* __restrict__ fc1_w1, const float* __restrict__ fc1_w2,
    float* __restrict__ m0, float* __restrict__ m1)
{
    __shared__ int hstore[4][1024];     // per-wave 64 rows x 64B
    __shared__ float sred[4][32];

    const int tid  = threadIdx.x;
    const int wv   = tid >> 6;
    const int lane = tid & 63;
    const int col  = lane & 15;
    const int g    = lane >> 4;
    const int dst  = blockIdx.x;

    for (int i = tid; i < 4096; i += 256) ((int*)hstore)[i] = 0;

    short8 w1f[7];
#pragma unroll
    for (int t = 0; t < 7; t++) w1f[t] = load_bfrag_pk<10,100>(fc1_w1, g*8, t*16 + col);
    short8 w2f[4];
#pragma unroll
    for (int s = 0; s < 4; s++) w2f[s] = load_bfrag_pk<100,16>(fc1_w2, s*32 + g*8, col);

    const float qx = pos[dst*3+0], qy = pos[dst*3+1], qz = pos[dst*3+2];
    float accm[4]    = {0.f,0.f,0.f,0.f};
    float accv[4][3] = {{0,0,0},{0,0,0},{0,0,0},{0,0,0}};

    __syncthreads();

    char* hb = (char*)&hstore[wv][0];
    const int wX = g >> 1;
    const int rX = g & 1;
    const int cb = col * 4;

    // pos prefetch for tile 0
    float pnx = pos[(wv*256 + col)*3 + 0];
    float pny = pos[(wv*256 + col)*3 + 1];
    float pnz = pos[(wv*256 + col)*3 + 2];

    for (int tile = 0; tile < 16; ++tile){
        const int src = wv*256 + tile*16 + col;
        const float cpx = pnx, cpy = pny, cpz = pnz;
        if (tile < 15){
            const int sn = src + 16;
            pnx = pos[sn*3+0]; pny = pos[sn*3+1]; pnz = pos[sn*3+2];
        }
        // hoisted epilogue load: latency hides under GEMM1+GEMM2
        f32x4 xe4 = *(const f32x4*)&xl[src*8 + 4*(g&1)];

        float dx = cpx-qx, dy = cpy-qy, dz = cpz-qz;
        float r2 = dx*dx + dy*dy + dz*dz;
        bool valid = (src != dst);
        float rinv = valid ? __builtin_amdgcn_rsqf(r2) : 0.f;
        float r    = valid ? r2*rinv : 1e9f;   // huge r -> emb underflows to 0
        float sf = SQ3_ * rinv;
        float y1x = dx*sf, y1y = dy*sf, y1z = dz*sf;
        short8 af;
        {
            float e0_ = r*INV_STEP_ - (float)(g<<3);
            float v[8];
#pragma unroll
            for (int e = 0; e < 8; e++){
                float d = e0_ - (float)e;
                v[e] = __builtin_amdgcn_exp2f((d*d) * (-LOG2E_));  // sqrt(10) folded
            }
            union { short8 s8; int u[4]; } a_;
            a_.u[0] = cvt_pk(v[0], v[1]);
            a_.u[1] = cvt_pk(v[2], v[3]);
            a_.u[2] = cvt_pk(v[4], v[5]);
            a_.u[3] = cvt_pk(v[6], v[7]);
            af = a_.s8;
        }
        __builtin_amdgcn_s_setprio(1);
        f32x4 zero4 = {0.f,0.f,0.f,0.f};
        f32x4 c2 = {0.f,0.f,0.f,0.f};
        HF h0, h1, h2, h3;
        G1STEP(0); G1STEP(1);
        RD4(0, h0);
        G1STEP(2); G1STEP(3);
        c2 = __builtin_amdgcn_mfma_f32_16x16x32_bf16(w2f[0], h0.s8, c2, 0, 0, 0);
        RD4(1, h1);
        G1STEP(4); G1STEP(5);
        c2 = __builtin_amdgcn_mfma_f32_16x16x32_bf16(w2f[1], h1.s8, c2, 0, 0, 0);
        RD4(2, h2);
        G1STEP(6);
        c2 = __builtin_amdgcn_mfma_f32_16x16x32_bf16(w2f[2], h2.s8, c2, 0, 0, 0);
        RD4(3, h3);
        c2 = __builtin_amdgcn_mfma_f32_16x16x32_bf16(w2f[3], h3.s8, c2, 0, 0, 0);
        __builtin_amdgcn_s_setprio(0);
        // --- epilogue: per-lane src = col, u = 4g+rg
        if (g < 2){
#pragma unroll
            for (int rg = 0; rg < 4; rg++) accm[rg] += c2[rg] * xe4[rg];
        } else {
#pragma unroll
            for (int rg = 0; rg < 4; rg++){
                float q = c2[rg] * xe4[rg];
                accv[rg][0] += q*y1x; accv[rg][1] += q*y1y; accv[rg][2] += q*y1z;
            }
        }
    }
    // reduce over the 16 src-cols within each g-group
#pragma unroll
    for (int off = 1; off <= 8; off <<= 1){
#pragma unroll
        for (int rg = 0; rg < 4; rg++){
            accm[rg] += __shfl_xor(accm[rg], off);
            accv[rg][0] += __shfl_xor(accv[rg][0], off);
            accv[rg][1] += __shfl_xor(accv[rg][1], off);
            accv[rg][2] += __shfl_xor(accv[rg][2], off);
        }
    }
    if (col == 0){
        if (g < 2){
#pragma unroll
            for (int rg = 0; rg < 4; rg++) sred[wv][4*g + rg] = accm[rg];
        } else {
#pragma unroll
            for (int rg = 0; rg < 4; rg++)
#pragma unroll
                for (int c = 0; c < 3; c++)
                    sred[wv][8 + (4*(g-2) + rg)*3 + c] = accv[rg][c];
        }
    }
    __syncthreads();
    if (tid < 32){
        float v = (sred[0][tid] + sred[1][tid]) + (sred[2][tid] + sred[3][tid]);
        v *= INV_NN_ * 0.1f;
        if (tid < 8) m0[dst*8 + tid] = v;
        else         m1[dst*24 + (tid - 8)] = v;
    }
}

// ---------------- Kernel C: node middle (a0 folded into a1np.w)
__global__ __launch_bounds__(64) void k_node_mid(
    const float* __restrict__ m0, const float* __restrict__ m1,
    const float* __restrict__ sc,
    const float* __restrict__ lin2a0, const float* __restrict__ lin2a1,
    const float* __restrict__ alpha1_w, const float* __restrict__ sc2_w,
    const float* __restrict__ lin1b0, const float* __restrict__ lin1b1,
    float* __restrict__ a1np, float* __restrict__ scv)
{
    int n = blockIdx.x * blockDim.x + threadIdx.x;
    if (n >= NND) return;
    float fm0[8];
#pragma unroll
    for (int u = 0; u < 8; u++) fm0[u] = m0[n*8 + u];
    float alpha = 0.f;
#pragma unroll
    for (int u = 0; u < 8; u++) alpha += fm0[u] * alpha1_w[u];
    alpha *= INV_S8_;

    float x0[16], gate[16];
#pragma unroll
    for (int k = 0; k < 32; k++){
        float o = 0.f;
#pragma unroll
        for (int u = 0; u < 8; u++) o += fm0[u] * lin2a0[u*32 + k];
        float sv = sc[n*32 + k] + alpha * (o * INV_S8_);
        if (k < 16) x0[k] = silu_f(sv);
        else        gate[k - 16] = sigm_f(sv);
    }
    float fm1[8][3];
#pragma unroll
    for (int u = 0; u < 8; u++)
#pragma unroll
        for (int c = 0; c < 3; c++) fm1[u][c] = m1[n*24 + u*3 + c];

    float x1[16][3];
#pragma unroll
    for (int v = 0; v < 16; v++){
        float o0 = 0.f, o1 = 0.f, o2 = 0.f;
#pragma unroll
        for (int u = 0; u < 8; u++){
            float wv = lin2a1[u*16 + v];
            o0 += fm1[u][0] * wv; o1 += fm1[u][1] * wv; o2 += fm1[u][2] * wv;
        }
        x1[v][0] = o0 * INV_S8_ * gate[v];
        x1[v][1] = o1 * INV_S8_ * gate[v];
        x1[v][2] = o2 * INV_S8_ * gate[v];
    }
    float s0 = 0.f, s1 = 0.f, s2 = 0.f;
#pragma unroll
    for (int u = 0; u < 16; u++){
        float wv = sc2_w[u];
        s0 += x1[u][0]*wv; s1 += x1[u][1]*wv; s2 += x1[u][2]*wv;
    }
    scv[n*3+0] = s0 * 0.25f; scv[n*3+1] = s1 * 0.25f; scv[n*3+2] = s2 * 0.25f;
#pragma unroll
    for (int v = 0; v < 16; v++){
        float a = 0.f;
#pragma unroll
        for (int u = 0; u < 16; u++) a += x0[u] * lin1b0[u*16 + v];
        float b0 = 0.f, b1 = 0.f, b2 = 0.f;
#pragma unroll
        for (int u = 0; u < 16; u++){
            float wv = lin1b1[u*16 + v];
            b0 += x1[u][0]*wv; b1 += x1[u][1]*wv; b2 += x1[u][2]*wv;
        }
        a1np[n*64 + v*4 + 0] = b0 * 0.25f;
        a1np[n*64 + v*4 + 1] = b1 * 0.25f;
        a1np[n*64 + v*4 + 2] = b2 * 0.25f;
        a1np[n*64 + v*4 + 3] = a  * 0.25f;   // a0 in .w
    }
}

// ---------------- Kernel D: edge pass 2 (within-tile pipelined MFMA)
__global__ __launch_bounds__(256,2) void k_edge2_mfma(
    const float* __restrict__ pos, const float* __restrict__ a1np,
    const float* __restrict__ fc2_w1, const float* __restrict__ fc2_w2,
    float* __restrict__ n0, float* __restrict__ n1)
{
    __shared__ int hstore[4][1024];
    __shared__ float sred[4][16][8];

    const int tid  = threadIdx.x;
    const int wv   = tid >> 6;
    const int lane = tid & 63;
    const int col  = lane & 15;
    const int g    = lane >> 4;
    const int dst  = blockIdx.x;

    for (int i = tid; i < 4096; i += 256) ((int*)hstore)[i] = 0;

    short8 w1f[7];
#pragma unroll
    for (int t = 0; t < 7; t++) w1f[t] = load_bfrag_pk<10,100>(fc2_w1, g*8, t*16 + col);
    short8 w2f[4][4];   // [kstep][qtile]: q -> wa/wb/wc/wd
#pragma unroll
    for (int s = 0; s < 4; s++)
#pragma unroll
        for (int q = 0; q < 4; q++)
            w2f[s][q] = load_bfrag_pk<100,64>(fc2_w2, s*32 + g*8, q*16 + col);

    const float qx = pos[dst*3+0], qy = pos[dst*3+1], qz = pos[dst*3+2];
    float acc[4][8];
#pragma unroll
    for (int a = 0; a < 4; a++)
#pragma unroll
        for (int b = 0; b < 8; b++) acc[a][b] = 0.f;

    __syncthreads();

    char* hb = (char*)&hstore[wv][0];
    const int wX = g >> 1;
    const int rX = g & 1;
    const int cb = col * 4;

    // pos prefetch for tile 0
    float pnx = pos[(wv*256 + col)*3 + 0];
    float pny = pos[(wv*256 + col)*3 + 1];
    float pnz = pos[(wv*256 + col)*3 + 2];

    for (int tile = 0; tile < 16; ++tile){
        const int src = wv*256 + tile*16 + col;
        const float cpx = pnx, cpy = pny, cpz = pnz;
        if (tile < 15){
            const int sn = src + 16;
            pnx = pos[sn*3+0]; pny = pos[sn*3+1]; pnz = pos[sn*3+2];
        }
        // hoisted epilogue loads: latency hides under GEMM1+GEMM2
        f32x4 av0 = *(const f32x4*)&a1np[src*64 + (4*g+0)*4];
        f32x4 av1 = *(const f32x4*)&a1np[src*64 + (4*g+1)*4];
        f32x4 av2 = *(const f32x4*)&a1np[src*64 + (4*g+2)*4];
        f32x4 av3 = *(const f32x4*)&a1np[src*64 + (4*g+3)*4];

        float dx = cpx-qx, dy = cpy-qy, dz = cpz-qz;
        float r2 = dx*dx + dy*dy + dz*dz;
        bool valid = (src != dst);
        float rinv = valid ? __builtin_amdgcn_rsqf(r2) : 0.f;
        float r    = valid ? r2*rinv : 1e9f;
        float sf = SQ3_ * rinv;
        float y1x = dx*sf, y1y = dy*sf, y1z = dz*sf;
        short8 af;
        {
            float e0_ = r*INV_STEP_ - (float)(g<<3);
            float v[8];
#pragma unroll
            for (int e = 0; e < 8; e++){
                float d = e0_ - (float)e;
                v[e] = __builtin_amdgcn_exp2f((d*d) * (-LOG2E_));
            }
            union { short8 s8; int u[4]; } a_;
            a_.u[0] = cvt_pk(v[0], v[1]);
            a_.u[1] = cvt_pk(v[2], v[3]);
            a_.u[2] = cvt_pk(v[4], v[5]);
            a_.u[3] = cvt_pk(v[6], v[7]);
            af = a_.s8;
        }
        __builtin_amdgcn_s_setprio(1);
        f32x4 zero4 = {0.f,0.f,0.f,0.f};
        f32x4 c20 = {0,0,0,0}, c21 = {0,0,0,0}, c22 = {0,0,0,0}, c23 = {0,0,0,0};
        HF h0, h1, h2, h3;
#define G2STEP(s, u_) do { \
        c20 = __builtin_amdgcn_mfma_f32_16x16x32_bf16(w2f[s][0], u_.s8, c20, 0, 0, 0); \
        c21 = __builtin_amdgcn_mfma_f32_16x16x32_bf16(w2f[s][1], u_.s8, c21, 0, 0, 0); \
        c22 = __builtin_amdgcn_mfma_f32_16x16x32_bf16(w2f[s][2], u_.s8, c22, 0, 0, 0); \
        c23 = __builtin_amdgcn_mfma_f32_16x16x32_bf16(w2f[s][3], u_.s8, c23, 0, 0, 0); \
} while(0)
        G1STEP(0); G1STEP(1);
        RD4(0, h0);
        G1STEP(2); G1STEP(3);
        G2STEP(0, h0);
        RD4(1, h1);
        G1STEP(4); G1STEP(5);
        G2STEP(1, h1);
        RD4(2, h2);
        G1STEP(6);
        G2STEP(2, h2);
        RD4(3, h3);
        G2STEP(3, h3);
#undef G2STEP
        __builtin_amdgcn_s_setprio(0);
        // --- epilogue: per-lane src = col, u = 4g+rg; A=c20,B=c21,C=c22,D=c23
#define EPI(rg, av) { \
            float A = c20[rg], B = c21[rg], Cc = c22[rg], D = c23[rg]; \
            acc[rg][0] += A * av[3]; \
            float dv = av[0]*y1x + av[1]*y1y + av[2]*y1z; \
            acc[rg][1] += D * dv; \
            float t2 = B * av[3]; \
            acc[rg][2] += t2*y1x; acc[rg][3] += t2*y1y; acc[rg][4] += t2*y1z; \
            acc[rg][5] += Cc*av[0]; acc[rg][6] += Cc*av[1]; acc[rg][7] += Cc*av[2]; }
        EPI(0, av0) EPI(1, av1) EPI(2, av2) EPI(3, av3)
#undef EPI
    }
    // reduce over the 16 src-cols
#pragma unroll
    for (int off = 1; off <= 8; off <<= 1)
#pragma unroll
        for (int a = 0; a < 4; a++)
#pragma unroll
            for (int b = 0; b < 8; b++) acc[a][b] += __shfl_xor(acc[a][b], off);
    if (col == 0){
#pragma unroll
        for (int rg = 0; rg < 4; rg++)
#pragma unroll
            for (int b = 0; b < 8; b++) sred[wv][4*g + rg][b] = acc[rg][b];
    }
    __syncthreads();
    if (tid < 128){
        int u = tid >> 3, cp = tid & 7;
        float v = sred[0][u][cp] + sred[1][u][cp] + sred[2][u][cp] + sred[3][u][cp];
        v *= INV_NN_ * 0.1f;
        if      (cp == 0) n0[dst*32 + u] = v;
        else if (cp == 1) n0[dst*32 + 16 + u] = v * INV_SQ3_;
        else if (cp < 5)  n1[dst*96 + u*3 + (cp-2)] = v;
        else              n1[dst*96 + (16+u)*3 + (cp-5)] = v;
    }
}

// ---------------- Kernel E1: final per-node combine, 16-way parallel partials
__global__ __launch_bounds__(64) void k_final_part(
    const float* __restrict__ n0, const float* __restrict__ n1,
    const float* __restrict__ scv, const float* __restrict__ lin2b,
    const float* __restrict__ alpha2_w, float* __restrict__ fpart)
{
    const int n = blockIdx.x * 64 + threadIdx.x;   // 16 blocks x 64 = 1024 nodes
    float ov0 = 0.f, ov1 = 0.f, ov2 = 0.f, al = 0.f;
#pragma unroll
    for (int u = 0; u < 32; u++){
        float w = lin2b[u];
        ov0 += n1[n*96 + u*3 + 0] * w;
        ov1 += n1[n*96 + u*3 + 1] * w;
        ov2 += n1[n*96 + u*3 + 2] * w;
        al  += n0[n*32 + u] * alpha2_w[u];
    }
    al *= INV_S32_;
    float acc0 = scv[n*3+0] + al * ov0 * INV_S32_;
    float acc1 = scv[n*3+1] + al * ov1 * INV_S32_;
    float acc2 = scv[n*3+2] + al * ov2 * INV_S32_;
#pragma unroll
    for (int off = 32; off > 0; off >>= 1){
        acc0 += __shfl_down(acc0, off);
        acc1 += __shfl_down(acc1, off);
        acc2 += __shfl_down(acc2, off);
    }
    if (threadIdx.x == 0){
        fpart[blockIdx.x*3 + 0] = acc0;
        fpart[blockIdx.x*3 + 1] = acc1;
        fpart[blockIdx.x*3 + 2] = acc2;
    }
}

// ---------------- Kernel E2: finish (sum 16 partials -> out[3])
__global__ __launch_bounds__(64) void k_final2(
    const float* __restrict__ fpart, float* __restrict__ out)
{
    const int l = threadIdx.x;
    float v0 = (l < 16) ? fpart[l*3 + 0] : 0.f;
    float v1 = (l < 16) ? fpart[l*3 + 1] : 0.f;
    float v2 = (l < 16) ? fpart[l*3 + 2] : 0.f;
#pragma unroll
    for (int off = 8; off > 0; off >>= 1){
        v0 += __shfl_down(v0, off);
        v1 += __shfl_down(v1, off);
        v2 += __shfl_down(v2, off);
    }
    if (l == 0){
        out[0] = v0 * (1.0f/32.0f);   // 1/sqrt(1024)
        out[1] = v1 * (1.0f/32.0f);
        out[2] = v2 * (1.0f/32.0f);
    }
}

extern "C" void kernel_launch(void* const* d_in, const int* in_sizes, int n_in,
                              void* d_out, int out_size, void* d_ws, size_t ws_size,
                              hipStream_t stream)
{
    const float* pos      = (const float*)d_in[0];
    const float* x        = (const float*)d_in[1];
    // d_in[2], d_in[3]: edge_src/edge_dst — dense all-pairs graph, enumerated directly
    const float* sc1_w    = (const float*)d_in[4];
    const float* lin1a_w  = (const float*)d_in[5];
    const float* fc1_w1   = (const float*)d_in[6];
    const float* fc1_w2   = (const float*)d_in[7];
    const float* lin2a0   = (const float*)d_in[8];
    const float* lin2a1   = (const float*)d_in[9];
    const float* alpha1_w = (const float*)d_in[10];
    const float* sc2_w    = (const float*)d_in[11];
    const float* lin1b0   = (const float*)d_in[12];
    const float* lin1b1   = (const float*)d_in[13];
    const float* fc2_w1   = (const float*)d_in[14];
    const float* fc2_w2   = (const float*)d_in[15];
    const float* lin2b    = (const float*)d_in[16];
    const float* alpha2_w = (const float*)d_in[17];

    float* ws    = (float*)d_ws;
    float* sc    = ws;               // 1024*32
    float* xl    = sc    + 32768;    // 1024*8
    float* m0    = xl    + 8192;     // 1024*8
    float* m1    = m0    + 8192;     // 1024*24
    float* a1np  = m1    + 24576;    // 1024*64 (a1 xyz + a0 in .w)
    float* scv   = a1np  + 65536;    // 1024*3
    float* n1    = scv   + 3072;     // 1024*96
    float* fpart = n1    + 98304;    // 16*3 partials
    float* n0    = m0;               // alias m0+m1 (32768 floats), dead after k_node_mid

    k_node_pre<<<16, 64, 0, stream>>>(x, sc1_w, lin1a_w, sc, xl);
    k_edge1_mfma<<<NND, 256, 0, stream>>>(pos, xl, fc1_w1, fc1_w2, m0, m1);
    k_node_mid<<<16, 64, 0, stream>>>(m0, m1, sc, lin2a0, lin2a1, alpha1_w, sc2_w,
                                      lin1b0, lin1b1, a1np, scv);
    k_edge2_mfma<<<NND, 256, 0, stream>>>(pos, a1np, fc2_w1, fc2_w2, n0, n1);
    k_final_part<<<16, 64, 0, stream>>>(n0, n1, scv, lin2b, alpha2_w, fpart);
    k_final2<<<1, 64, 0, stream>>>(fpart, (float*)d_out);
}

// Round 14
// 159.879 us; speedup vs baseline: 1.0021x; 1.0021x over previous
//
#include <hip/hip_runtime.h>
#include <math.h>

#define NND 1024

#define STEP_     (5.0f/9.0f)
#define INV_STEP_ 1.8f
#define SQ3_      1.73205080756887729f
#define INV_SQ3_  0.57735026918962576f
#define INV_NN_   0.03126527053f      /* 1/sqrt(1023) */
#define INV_S8_   0.35355339059327373f
#define INV_S32_  0.17677669529663687f
#define LOG2E_    1.44269504088896341f

typedef float f32x4 __attribute__((ext_vector_type(4)));
typedef short short8 __attribute__((ext_vector_type(8)));

__device__ __forceinline__ float fast_rcp(float x){ return __builtin_amdgcn_rcpf(x); }
__device__ __forceinline__ float silu_f(float t){
    return t * fast_rcp(1.0f + __builtin_amdgcn_exp2f(t * (-LOG2E_)));
}
__device__ __forceinline__ float sigm_f(float t){
    return fast_rcp(1.0f + __builtin_amdgcn_exp2f(t * (-LOG2E_)));
}
// packed bf16 convert. Internal half order σ UNKNOWN — every use pairs the SAME
// even-k (x[k0],x[k0+1]) structure on BOTH MFMA operands, so σ cancels.
__device__ __forceinline__ int cvt_pk(float a, float b){
    int r;
    asm("v_cvt_pk_bf16_f32 %0, %1, %2" : "=v"(r) : "v"(a), "v"(b));
    return r;
}

// fragment via cvt_pk pairs: lane holds m/n = ncol, k = kbase + [dword i covers
// k0=kbase+2i, k0+1 in σ-order]. Pairs with any other cvt_pk-built operand.
template<int KREAL, int NCOLS>
__device__ __forceinline__ short8 load_bfrag_pk(const float* __restrict__ W, int kbase, int ncol){
    union { short8 s8; int u[4]; } f;
#pragma unroll
    for (int i = 0; i < 4; i++){
        int k0 = kbase + 2*i, k1 = k0 + 1;
        float v0 = (k0 < KREAL && ncol < NCOLS) ? W[k0*NCOLS + ncol] : 0.f;
        float v1 = (k1 < KREAL && ncol < NCOLS) ? W[k1*NCOLS + ncol] : 0.f;
        f.u[i] = cvt_pk(v0, v1);
    }
    return f.s8;
}

// hT staging (dword layout = round 6/7/10/12, verified passing):
// h[j][src] pairs (j0=2R, j0+1) in dword at byte (R^xbit)*64 + src*4.
// Write: R = 8t+2g+p, xbit = g>>1.  Read: R = 16s+4g+i, xbit = g&1.

// ---------------- Kernel A: node pre-GEMMs
__global__ __launch_bounds__(64) void k_node_pre(
    const float* __restrict__ x, const float* __restrict__ sc1_w,
    const float* __restrict__ lin1a_w, float* __restrict__ sc, float* __restrict__ xl)
{
    int n = blockIdx.x * blockDim.x + threadIdx.x;
    if (n >= NND) return;
    float xi[8];
#pragma unroll
    for (int i = 0; i < 8; i++) xi[i] = x[n*8 + i];
#pragma unroll
    for (int k = 0; k < 32; k++){
        float a = 0.f;
#pragma unroll
        for (int i = 0; i < 8; i++) a += xi[i] * sc1_w[i*32 + k];
        sc[n*32 + k] = a * INV_S8_;
    }
#pragma unroll
    for (int k = 0; k < 8; k++){
        float a = 0.f;
#pragma unroll
        for (int i = 0; i < 8; i++) a += xi[i] * lin1a_w[i*8 + k];
        xl[n*8 + k] = a * INV_S8_;
    }
}

// ---------------- Kernel B: edge pass 1 — SPLIT: 2 blocks per dst (512 srcs each)
// edge1 is grid-limited (VGPR=64 -> 32 waves/CU allowed; grid 1024 gave only 16).
// Grid 2048 -> 8 blocks/CU -> doubles resident waves. Partial m0/m1 per half.
__global__ __launch_bounds__(256,3) void k_edge1_mfma(
    const float* __restrict__ pos, const float* __restrict__ xl,
    const float* __restrict__ fc1_w1, const float* __restrict__ fc1_w2,
    float* __restrict__ m0p, float* __restrict__ m1p)
{
    __shared__ int hstore[4][1024];     // per-wave 64 rows x 64B
    __shared__ float sred[4][32];

    const int tid  = threadIdx.x;
    const int wv   = tid >> 6;
    const int lane = tid & 63;
    const int col  = lane & 15;
    const int g    = lane >> 4;
    const int dst  = blockIdx.x >> 1;
    const int half = blockIdx.x & 1;
    const int sbase0 = half*512 + wv*128;   // this wave covers 128 srcs in 8 tiles

    for (int i = tid; i < 4096; i += 256) ((int*)hstore)[i] = 0;

    short8 w1f[7];
#pragma unroll
    for (int t = 0; t < 7; t++) w1f[t] = load_bfrag_pk<10,100>(fc1_w1, g*8, t*16 + col);
    short8 w2f[4];
#pragma unroll
    for (int s = 0; s < 4; s++) w2f[s] = load_bfrag_pk<100,16>(fc1_w2, s*32 + g*8, col);

    const float qx = pos[dst*3+0], qy = pos[dst*3+1], qz = pos[dst*3+2];
    float accm[4]    = {0.f,0.f,0.f,0.f};
    float accv[4][3] = {{0,0,0},{0,0,0},{0,0,0},{0,0,0}};

    __syncthreads();

    char* hb = (char*)&hstore[wv][0];
    const int wX = g >> 1;
    const int rX = g & 1;
    const int cb = col * 4;

    // pos prefetch for tile 0
    float pnx = pos[(sbase0 + col)*3 + 0];
    float pny = pos[(sbase0 + col)*3 + 1];
    float pnz = pos[(sbase0 + col)*3 + 2];

    for (int tile = 0; tile < 8; ++tile){
        const int src = sbase0 + tile*16 + col;
        const float cpx = pnx, cpy = pny, cpz = pnz;
        if (tile < 7){
            const int sn = src + 16;
            pnx = pos[sn*3+0]; pny = pos[sn*3+1]; pnz = pos[sn*3+2];
        }
        // hoisted epilogue load: latency hides under GEMM1+GEMM2
        f32x4 xe4 = *(const f32x4*)&xl[src*8 + 4*(g&1)];

        float dx = cpx-qx, dy = cpy-qy, dz = cpz-qz;
        float r2 = dx*dx + dy*dy + dz*dz;
        bool valid = (src != dst);
        float rinv = valid ? __builtin_amdgcn_rsqf(r2) : 0.f;
        float r    = valid ? r2*rinv : 1e9f;   // huge r -> emb underflows to 0
        float sf = SQ3_ * rinv;
        float y1x = dx*sf, y1y = dy*sf, y1z = dz*sf;
        short8 af;
        {
            float e0_ = r*INV_STEP_ - (float)(g<<3);
            float v[8];
#pragma unroll
            for (int e = 0; e < 8; e++){
                float d = e0_ - (float)e;
                v[e] = __builtin_amdgcn_exp2f((d*d) * (-LOG2E_));  // sqrt(10) folded
            }
            union { short8 s8; int u[4]; } a_;
            a_.u[0] = cvt_pk(v[0], v[1]);
            a_.u[1] = cvt_pk(v[2], v[3]);
            a_.u[2] = cvt_pk(v[4], v[5]);
            a_.u[3] = cvt_pk(v[6], v[7]);
            af = a_.s8;
        }
        __builtin_amdgcn_s_setprio(1);
        // --- GEMM1 (swapped): c1[rg] = h-pre[j = 16t+4g+rg][src=col]
        f32x4 zero4 = {0.f,0.f,0.f,0.f};
#pragma unroll
        for (int t = 0; t < 7; t++){
            f32x4 c1 = __builtin_amdgcn_mfma_f32_16x16x32_bf16(w1f[t], af, zero4, 0, 0, 0);
            int R0 = 8*t + 2*g;
            *(int*)(hb + (((R0    ) ^ wX) << 6) + cb) = cvt_pk(silu_f(c1[0]), silu_f(c1[1]));
            *(int*)(hb + (((R0 + 1) ^ wX) << 6) + cb) = cvt_pk(silu_f(c1[2]), silu_f(c1[3]));
        }
        // --- GEMM2 (swapped): c2[rg] = W[u = 4g+rg][src = col]
        f32x4 c2 = {0.f,0.f,0.f,0.f};
#pragma unroll
        for (int s = 0; s < 4; s++){
            union { short8 s8; int i4[4]; } hf;
#pragma unroll
            for (int i = 0; i < 4; i++)
                hf.i4[i] = *(const int*)(hb + (((16*s + 4*g + i) ^ rX) << 6) + cb);
            c2 = __builtin_amdgcn_mfma_f32_16x16x32_bf16(w2f[s], hf.s8, c2, 0, 0, 0);
        }
        __builtin_amdgcn_s_setprio(0);
        // --- epilogue: per-lane src = col, u = 4g+rg
        if (g < 2){
#pragma unroll
            for (int rg = 0; rg < 4; rg++) accm[rg] += c2[rg] * xe4[rg];
        } else {
#pragma unroll
            for (int rg = 0; rg < 4; rg++){
                float q = c2[rg] * xe4[rg];
                accv[rg][0] += q*y1x; accv[rg][1] += q*y1y; accv[rg][2] += q*y1z;
            }
        }
    }
    // reduce over the 16 src-cols within each g-group
#pragma unroll
    for (int off = 1; off <= 8; off <<= 1){
#pragma unroll
        for (int rg = 0; rg < 4; rg++){
            accm[rg] += __shfl_xor(accm[rg], off);
            accv[rg][0] += __shfl_xor(accv[rg][0], off);
            accv[rg][1] += __shfl_xor(accv[rg][1], off);
            accv[rg][2] += __shfl_xor(accv[rg][2], off);
        }
    }
    if (col == 0){
        if (g < 2){
#pragma unroll
            for (int rg = 0; rg < 4; rg++) sred[wv][4*g + rg] = accm[rg];
        } else {
#pragma unroll
            for (int rg = 0; rg < 4; rg++)
#pragma unroll
                for (int c = 0; c < 3; c++)
                    sred[wv][8 + (4*(g-2) + rg)*3 + c] = accv[rg][c];
        }
    }
    __syncthreads();
    if (tid < 32){
        float v = (sred[0][tid] + sred[1][tid]) + (sred[2][tid] + sred[3][tid]);
        v *= INV_NN_ * 0.1f;
        float* m0o = m0p + half*8192;     // partial buffers; node_mid sums halves
        float* m1o = m1p + half*24576;
        if (tid < 8) m0o[dst*8 + tid] = v;
        else         m1o[dst*24 + (tid - 8)] = v;
    }
}

// ---------------- Kernel C: node middle (sums edge1's two partial halves)
__global__ __launch_bounds__(64) void k_node_mid(
    const float* __restrict__ m0p, const float* __restrict__ m1p,
    const float* __restrict__ sc,
    const float* __restrict__ lin2a0, const float* __restrict__ lin2a1,
    const float* __restrict__ alpha1_w, const float* __restrict__ sc2_w,
    const float* __restrict__ lin1b0, const float* __restrict__ lin1b1,
    float* __restrict__ a1np, float* __restrict__ scv)
{
    int n = blockIdx.x * blockDim.x + threadIdx.x;
    if (n >= NND) return;
    float fm0[8];
#pragma unroll
    for (int u = 0; u < 8; u++) fm0[u] = m0p[n*8 + u] + m0p[8192 + n*8 + u];
    float alpha = 0.f;
#pragma unroll
    for (int u = 0; u < 8; u++) alpha += fm0[u] * alpha1_w[u];
    alpha *= INV_S8_;

    float x0[16], gate[16];
#pragma unroll
    for (int k = 0; k < 32; k++){
        float o = 0.f;
#pragma unroll
        for (int u = 0; u < 8; u++) o += fm0[u] * lin2a0[u*32 + k];
        float sv = sc[n*32 + k] + alpha * (o * INV_S8_);
        if (k < 16) x0[k] = silu_f(sv);
        else        gate[k - 16] = sigm_f(sv);
    }
    float fm1[8][3];
#pragma unroll
    for (int u = 0; u < 8; u++)
#pragma unroll
        for (int c = 0; c < 3; c++)
            fm1[u][c] = m1p[n*24 + u*3 + c] + m1p[24576 + n*24 + u*3 + c];

    float x1[16][3];
#pragma unroll
    for (int v = 0; v < 16; v++){
        float o0 = 0.f, o1 = 0.f, o2 = 0.f;
#pragma unroll
        for (int u = 0; u < 8; u++){
            float wv = lin2a1[u*16 + v];
            o0 += fm1[u][0] * wv; o1 += fm1[u][1] * wv; o2 += fm1[u][2] * wv;
        }
        x1[v][0] = o0 * INV_S8_ * gate[v];
        x1[v][1] = o1 * INV_S8_ * gate[v];
        x1[v][2] = o2 * INV_S8_ * gate[v];
    }
    float s0 = 0.f, s1 = 0.f, s2 = 0.f;
#pragma unroll
    for (int u = 0; u < 16; u++){
        float wv = sc2_w[u];
        s0 += x1[u][0]*wv; s1 += x1[u][1]*wv; s2 += x1[u][2]*wv;
    }
    scv[n*3+0] = s0 * 0.25f; scv[n*3+1] = s1 * 0.25f; scv[n*3+2] = s2 * 0.25f;
#pragma unroll
    for (int v = 0; v < 16; v++){
        float a = 0.f;
#pragma unroll
        for (int u = 0; u < 16; u++) a += x0[u] * lin1b0[u*16 + v];
        float b0 = 0.f, b1 = 0.f, b2 = 0.f;
#pragma unroll
        for (int u = 0; u < 16; u++){
            float wv = lin1b1[u*16 + v];
            b0 += x1[u][0]*wv; b1 += x1[u][1]*wv; b2 += x1[u][2]*wv;
        }
        a1np[n*64 + v*4 + 0] = b0 * 0.25f;
        a1np[n*64 + v*4 + 1] = b1 * 0.25f;
        a1np[n*64 + v*4 + 2] = b2 * 0.25f;
        a1np[n*64 + v*4 + 3] = a  * 0.25f;   // a0 in .w
    }
}

// ---------------- Kernel D: edge pass 2 (r12-verified)
__global__ __launch_bounds__(256,2) void k_edge2_mfma(
    const float* __restrict__ pos, const float* __restrict__ a1np,
    const float* __restrict__ fc2_w1, const float* __restrict__ fc2_w2,
    float* __restrict__ n0, float* __restrict__ n1)
{
    __shared__ int hstore[4][1024];
    __shared__ float sred[4][16][8];

    const int tid  = threadIdx.x;
    const int wv   = tid >> 6;
    const int lane = tid & 63;
    const int col  = lane & 15;
    const int g    = lane >> 4;
    const int dst  = blockIdx.x;

    for (int i = tid; i < 4096; i += 256) ((int*)hstore)[i] = 0;

    short8 w1f[7];
#pragma unroll
    for (int t = 0; t < 7; t++) w1f[t] = load_bfrag_pk<10,100>(fc2_w1, g*8, t*16 + col);
    short8 w2f[4][4];   // [kstep][qtile]: q -> wa/wb/wc/wd
#pragma unroll
    for (int s = 0; s < 4; s++)
#pragma unroll
        for (int q = 0; q < 4; q++)
            w2f[s][q] = load_bfrag_pk<100,64>(fc2_w2, s*32 + g*8, q*16 + col);

    const float qx = pos[dst*3+0], qy = pos[dst*3+1], qz = pos[dst*3+2];
    float acc[4][8];
#pragma unroll
    for (int a = 0; a < 4; a++)
#pragma unroll
        for (int b = 0; b < 8; b++) acc[a][b] = 0.f;

    __syncthreads();

    char* hb = (char*)&hstore[wv][0];
    const int wX = g >> 1;
    const int rX = g & 1;
    const int cb = col * 4;

    // pos prefetch for tile 0
    float pnx = pos[(wv*256 + col)*3 + 0];
    float pny = pos[(wv*256 + col)*3 + 1];
    float pnz = pos[(wv*256 + col)*3 + 2];

    for (int tile = 0; tile < 16; ++tile){
        const int src = wv*256 + tile*16 + col;
        const float cpx = pnx, cpy = pny, cpz = pnz;
        if (tile < 15){
            const int sn = src + 16;
            pnx = pos[sn*3+0]; pny = pos[sn*3+1]; pnz = pos[sn*3+2];
        }
        // hoisted epilogue loads: latency hides under GEMM1+GEMM2
        f32x4 av0 = *(const f32x4*)&a1np[src*64 + (4*g+0)*4];
        f32x4 av1 = *(const f32x4*)&a1np[src*64 + (4*g+1)*4];
        f32x4 av2 = *(const f32x4*)&a1np[src*64 + (4*g+2)*4];
        f32x4 av3 = *(const f32x4*)&a1np[src*64 + (4*g+3)*4];

        float dx = cpx-qx, dy = cpy-qy, dz = cpz-qz;
        float r2 = dx*dx + dy*dy + dz*dz;
        bool valid = (src != dst);
        float rinv = valid ? __builtin_amdgcn_rsqf(r2) : 0.f;
        float r    = valid ? r2*rinv : 1e9f;
        float sf = SQ3_ * rinv;
        float y1x = dx*sf, y1y = dy*sf, y1z = dz*sf;
        short8 af;
        {
            float e0_ = r*INV_STEP_ - (float)(g<<3);
            float v[8];
#pragma unroll
            for (int e = 0; e < 8; e++){
                float d = e0_ - (float)e;
                v[e] = __builtin_amdgcn_exp2f((d*d) * (-LOG2E_));
            }
            union { short8 s8; int u[4]; } a_;
            a_.u[0] = cvt_pk(v[0], v[1]);
            a_.u[1] = cvt_pk(v[2], v[3]);
            a_.u[2] = cvt_pk(v[4], v[5]);
            a_.u[3] = cvt_pk(v[6], v[7]);
            af = a_.s8;
        }
        __builtin_amdgcn_s_setprio(1);
        f32x4 zero4 = {0.f,0.f,0.f,0.f};
#pragma unroll
        for (int t = 0; t < 7; t++){
            f32x4 c1 = __builtin_amdgcn_mfma_f32_16x16x32_bf16(w1f[t], af, zero4, 0, 0, 0);
            int R0 = 8*t + 2*g;
            *(int*)(hb + (((R0    ) ^ wX) << 6) + cb) = cvt_pk(silu_f(c1[0]), silu_f(c1[1]));
            *(int*)(hb + (((R0 + 1) ^ wX) << 6) + cb) = cvt_pk(silu_f(c1[2]), silu_f(c1[3]));
        }
        // --- GEMM2: c2[q][rg] = W[u = q*16 + 4g+rg][src = col]
        f32x4 c20 = {0,0,0,0}, c21 = {0,0,0,0}, c22 = {0,0,0,0}, c23 = {0,0,0,0};
#pragma unroll
        for (int s = 0; s < 4; s++){
            union { short8 s8; int i4[4]; } hf;
#pragma unroll
            for (int i = 0; i < 4; i++)
                hf.i4[i] = *(const int*)(hb + (((16*s + 4*g + i) ^ rX) << 6) + cb);
            c20 = __builtin_amdgcn_mfma_f32_16x16x32_bf16(w2f[s][0], hf.s8, c20, 0, 0, 0);
            c21 = __builtin_amdgcn_mfma_f32_16x16x32_bf16(w2f[s][1], hf.s8, c21, 0, 0, 0);
            c22 = __builtin_amdgcn_mfma_f32_16x16x32_bf16(w2f[s][2], hf.s8, c22, 0, 0, 0);
            c23 = __builtin_amdgcn_mfma_f32_16x16x32_bf16(w2f[s][3], hf.s8, c23, 0, 0, 0);
        }
        __builtin_amdgcn_s_setprio(0);
        // --- epilogue: per-lane src = col, u = 4g+rg; A=c20,B=c21,C=c22,D=c23
#define EPI(rg, av) { \
            float A = c20[rg], B = c21[rg], Cc = c22[rg], D = c23[rg]; \
            acc[rg][0] += A * av[3]; \
            float dv = av[0]*y1x + av[1]*y1y + av[2]*y1z; \
            acc[rg][1] += D * dv; \
            float t2 = B * av[3]; \
            acc[rg][2] += t2*y1x; acc[rg][3] += t2*y1y; acc[rg][4] += t2*y1z; \
            acc[rg][5] += Cc*av[0]; acc[rg][6] += Cc*av[1]; acc[rg][7] += Cc*av[2]; }
        EPI(0, av0) EPI(1, av1) EPI(2, av2) EPI(3, av3)
#undef EPI
    }
    // reduce over the 16 src-cols
#pragma unroll
    for (int off = 1; off <= 8; off <<= 1)
#pragma unroll
        for (int a = 0; a < 4; a++)
#pragma unroll
            for (int b = 0; b < 8; b++) acc[a][b] += __shfl_xor(acc[a][b], off);
    if (col == 0){
#pragma unroll
        for (int rg = 0; rg < 4; rg++)
#pragma unroll
            for (int b = 0; b < 8; b++) sred[wv][4*g + rg][b] = acc[rg][b];
    }
    __syncthreads();
    if (tid < 128){
        int u = tid >> 3, cp = tid & 7;
        float v = sred[0][u][cp] + sred[1][u][cp] + sred[2][u][cp] + sred[3][u][cp];
        v *= INV_NN_ * 0.1f;
        if      (cp == 0) n0[dst*32 + u] = v;
        else if (cp == 1) n0[dst*32 + 16 + u] = v * INV_SQ3_;
        else if (cp < 5)  n1[dst*96 + u*3 + (cp-2)] = v;
        else              n1[dst*96 + (16+u)*3 + (cp-5)] = v;
    }
}

// ---------------- Kernel E1: final per-node combine, 16-way parallel partials
__global__ __launch_bounds__(64) void k_final_part(
    const float* __restrict__ n0, const float* __restrict__ n1,
    const float* __restrict__ scv, const float* __restrict__ lin2b,
    const float* __restrict__ alpha2_w, float* __restrict__ fpart)
{
    const int n = blockIdx.x * 64 + threadIdx.x;   // 16 blocks x 64 = 1024 nodes
    float ov0 = 0.f, ov1 = 0.f, ov2 = 0.f, al = 0.f;
#pragma unroll
    for (int u = 0; u < 32; u++){
        float w = lin2b[u];
        ov0 += n1[n*96 + u*3 + 0] * w;
        ov1 += n1[n*96 + u*3 + 1] * w;
        ov2 += n1[n*96 + u*3 + 2] * w;
        al  += n0[n*32 + u] * alpha2_w[u];
    }
    al *= INV_S32_;
    float acc0 = scv[n*3+0] + al * ov0 * INV_S32_;
    float acc1 = scv[n*3+1] + al * ov1 * INV_S32_;
    float acc2 = scv[n*3+2] + al * ov2 * INV_S32_;
#pragma unroll
    for (int off = 32; off > 0; off >>= 1){
        acc0 += __shfl_down(acc0, off);
        acc1 += __shfl_down(acc1, off);
        acc2 += __shfl_down(acc2, off);
    }
    if (threadIdx.x == 0){
        fpart[blockIdx.x*3 + 0] = acc0;
        fpart[blockIdx.x*3 + 1] = acc1;
        fpart[blockIdx.x*3 + 2] = acc2;
    }
}

// ---------------- Kernel E2: finish (sum 16 partials -> out[3])
__global__ __launch_bounds__(64) void k_final2(
    const float* __restrict__ fpart, float* __restrict__ out)
{
    const int l = threadIdx.x;
    float v0 = (l < 16) ? fpart[l*3 + 0] : 0.f;
    float v1 = (l < 16) ? fpart[l*3 + 1] : 0.f;
    float v2 = (l < 16) ? fpart[l*3 + 2] : 0.f;
#pragma unroll
    for (int off = 8; off > 0; off >>= 1){
        v0 += __shfl_down(v0, off);
        v1 += __shfl_down(v1, off);
        v2 += __shfl_down(v2, off);
    }
    if (l == 0){
        out[0] = v0 * (1.0f/32.0f);   // 1/sqrt(1024)
        out[1] = v1 * (1.0f/32.0f);
        out[2] = v2 * (1.0f/32.0f);
    }
}

extern "C" void kernel_launch(void* const* d_in, const int* in_sizes, int n_in,
                              void* d_out, int out_size, void* d_ws, size_t ws_size,
                              hipStream_t stream)
{
    const float* pos      = (const float*)d_in[0];
    const float* x        = (const float*)d_in[1];
    // d_in[2], d_in[3]: edge_src/edge_dst — dense all-pairs graph, enumerated directly
    const float* sc1_w    = (const float*)d_in[4];
    const float* lin1a_w  = (const float*)d_in[5];
    const float* fc1_w1   = (const float*)d_in[6];
    const float* fc1_w2   = (const float*)d_in[7];
    const float* lin2a0   = (const float*)d_in[8];
    const float* lin2a1   = (const float*)d_in[9];
    const float* alpha1_w = (const float*)d_in[10];
    const float* sc2_w    = (const float*)d_in[11];
    const float* lin1b0   = (const float*)d_in[12];
    const float* lin1b1   = (const float*)d_in[13];
    const float* fc2_w1   = (const float*)d_in[14];
    const float* fc2_w2   = (const float*)d_in[15];
    const float* lin2b    = (const float*)d_in[16];
    const float* alpha2_w = (const float*)d_in[17];

    float* ws    = (float*)d_ws;
    float* sc    = ws;               // 1024*32
    float* xl    = sc    + 32768;    // 1024*8
    float* m0p   = xl    + 8192;     // 2 x 1024*8  (edge1 partial halves)
    float* m1p   = m0p   + 16384;    // 2 x 1024*24
    float* a1np  = m1p   + 49152;    // 1024*64 (a1 xyz + a0 in .w)
    float* scv   = a1np  + 65536;    // 1024*3
    float* n1    = scv   + 3072;     // 1024*96
    float* fpart = n1    + 98304;    // 16*3 partials
    float* n0    = m0p;              // alias m0p+m1p region (65536 floats), dead after k_node_mid

    k_node_pre<<<16, 64, 0, stream>>>(x, sc1_w, lin1a_w, sc, xl);
    k_edge1_mfma<<<2*NND, 256, 0, stream>>>(pos, xl, fc1_w1, fc1_w2, m0p, m1p);
    k_node_mid<<<16, 64, 0, stream>>>(m0p, m1p, sc, lin2a0, lin2a1, alpha1_w, sc2_w,
                                      lin1b0, lin1b1, a1np, scv);
    k_edge2_mfma<<<NND, 256, 0, stream>>>(pos, a1np, fc2_w1, fc2_w2, n0, n1);
    k_final_part<<<16, 64, 0, stream>>>(n0, n1, scv, lin2b, alpha2_w, fpart);
    k_final2<<<1, 64, 0, stream>>>(fpart, (float*)d_out);
}